// Round 8
// baseline (8400.872 us; speedup 1.0000x reference)
//
// R17: halve the all-to-all width. R10/R12/R16 triangulation shows the step
// cost is ~6.3us FIXED (serial publish->ack->flag->poll-RT->gather-RT chain,
// amplified by max-of-32 straggler skew at the every-step barrier) + only
// ~45ps per sc1 request. Gather-path micro-opts are exhausted; the untouched
// parameter is the NUMBER OF PARTICIPANTS. Weights force 216 VGPR/lane for
// 9 rows/half-wave, but a 512-THREAD WG (16 half-waves) carries 144 rows at
// the same per-lane budget -> 16 WGs per XCD instead of 32. Same per-thread
// compute (864 FMA, 180 shfl); what halves: exchange width (skew max-of-16),
// flags (16), XCD-wide sc1 requests (12.3K vs 24.6K), publisher count.
// Protocol byte-identical to R12 (best passing, 1985us): sc1 flag damper +
// valve + s_sleep, sc1 untagged gather proven by the flag ordering, publish
// drained by __syncthreads before tid0's flag store, prep seeds buf0 + zeroes
// flags. Occupancy: 8 waves x <=256 VGPR = exactly 1 WG/CU (VGPR-forced; the
// LDS pad is no longer needed and is dropped).
#include <hip/hip_runtime.h>
#include <cstdint>
#include <cstddef>

#define H    768
#define G3   2304
#define TT   512
#define BS   32
#define NGRP 8
#define GWG  16        // worker WGs per group (512 threads each, 16 CUs used)
#define SPG  4         // samples per group
#define GRID_GRU 512   // oversubscribed; ticket winners persist

// ctrl block inside xg dead zone (b=0, t>=384; L[0]~256 => never touched)
#define WS_XG    0
#define WS_CTRL  3538944                 // byte offset of xg[0][384][0]
#define CT_TICK  0                       // uint[8]
#define CT_FLAGS 64                      // uint[8][16] = 512 B
#define CT_L     1088                    // int[32]
#define CT_HB    1280                    // float[8][2][3072] = 196608 B

typedef float vf4 __attribute__((ext_vector_type(4)));

// ---------------- phase 1: lengths + tickets/flags + hF buf0 seed -------------
__global__ void prep_kernel(const int* __restrict__ mask, const float* __restrict__ gc,
                            int* __restrict__ L, unsigned int* __restrict__ tick,
                            unsigned int* __restrict__ flags,
                            float* __restrict__ hF) {
    __shared__ int sbuf[256];
    const int b = blockIdx.x, tid = threadIdx.x;
    int c = 0;
    for (int t = tid; t < TT; t += 256) c += (mask[b * TT + t] != 0) ? 1 : 0;
    sbuf[tid] = c;
    __syncthreads();
    for (int off = 128; off > 0; off >>= 1) {
        if (tid < off) sbuf[tid] += sbuf[tid + off];
        __syncthreads();
    }
    if (tid == 0) {
        int l = sbuf[0];
        if (l < 1) l = 2;              // reference: where(L<1, 2, L)
        L[b] = l;
    }
    if (b == 0 && tid < NGRP) tick[tid] = 0u;
    if (tid < 4) flags[b * 4 + tid] = 0u;          // 32 blocks x 4 = 128
    // seed hF[g][buf0][r] = gc[r>>2]: 24576 floats, 768 per block (r = c*4+smp)
    for (int i = tid; i < 768; i += 256) {
        const int e = b * 768 + i;                 // 0..24575
        const int g = e / 3072, r = e - g * 3072;
        hF[g * 6144 + r] = gc[r >> 2];
    }
}

// ---------------- phase 2: xg = emb @ W_ih^T + b_ih (unchanged) ----------------
__global__ __launch_bounds__(256) void xg_gemm(
    const float* __restrict__ A, const float* __restrict__ W,
    const float* __restrict__ bih, const int* __restrict__ L,
    float* __restrict__ xg)
{
    const int mt = blockIdx.x, nt = blockIdx.y;
    const int b  = mt >> 3;
    const int t0 = (mt & 7) << 6;
    if (t0 >= L[b]) return;

    __shared__ __align__(16) float As[16][68];
    __shared__ __align__(16) float Bsh[16][68];

    const int tid = threadIdx.x;
    const int m0 = mt << 6, n0 = nt << 6;
    const int lr = tid >> 2;
    const int lk = (tid & 3) << 2;
    const int tm = (tid >> 4) << 2;
    const int tn = (tid & 15) << 2;

    float c[4][4] = {};
    const float* Ap = A + (size_t)(m0 + lr) * H + lk;
    const float* Wp = W + (size_t)(n0 + lr) * H + lk;

    for (int k0 = 0; k0 < H; k0 += 16) {
        float4 av = *(const float4*)(Ap + k0);
        float4 bv = *(const float4*)(Wp + k0);
        As[lk + 0][lr] = av.x; As[lk + 1][lr] = av.y;
        As[lk + 2][lr] = av.z; As[lk + 3][lr] = av.w;
        Bsh[lk + 0][lr] = bv.x; Bsh[lk + 1][lr] = bv.y;
        Bsh[lk + 2][lr] = bv.z; Bsh[lk + 3][lr] = bv.w;
        __syncthreads();
#pragma unroll
        for (int kk = 0; kk < 16; ++kk) {
            float4 a4 = *(const float4*)&As[kk][tm];
            float4 b4 = *(const float4*)&Bsh[kk][tn];
            c[0][0] = fmaf(a4.x, b4.x, c[0][0]); c[0][1] = fmaf(a4.x, b4.y, c[0][1]);
            c[0][2] = fmaf(a4.x, b4.z, c[0][2]); c[0][3] = fmaf(a4.x, b4.w, c[0][3]);
            c[1][0] = fmaf(a4.y, b4.x, c[1][0]); c[1][1] = fmaf(a4.y, b4.y, c[1][1]);
            c[1][2] = fmaf(a4.y, b4.z, c[1][2]); c[1][3] = fmaf(a4.y, b4.w, c[1][3]);
            c[2][0] = fmaf(a4.z, b4.x, c[2][0]); c[2][1] = fmaf(a4.z, b4.y, c[2][1]);
            c[2][2] = fmaf(a4.z, b4.z, c[2][2]); c[2][3] = fmaf(a4.z, b4.w, c[2][3]);
            c[3][0] = fmaf(a4.w, b4.x, c[3][0]); c[3][1] = fmaf(a4.w, b4.y, c[3][1]);
            c[3][2] = fmaf(a4.w, b4.z, c[3][2]); c[3][3] = fmaf(a4.w, b4.w, c[3][3]);
        }
        __syncthreads();
    }
    const float4 bias = *(const float4*)&bih[n0 + tn];
#pragma unroll
    for (int i = 0; i < 4; ++i) {
        float4 o;
        o.x = c[i][0] + bias.x; o.y = c[i][1] + bias.y;
        o.z = c[i][2] + bias.z; o.w = c[i][3] + bias.w;
        *(float4*)&xg[(size_t)(m0 + tm + i) * G3 + n0 + tn] = o;
    }
}

// ---------------- phase 3: per-XCD group of 16 WGs x 512 threads, 4 chains ---
__global__ __launch_bounds__(512, 2) void gru_kernel(
    const float* __restrict__ Whh, const float* __restrict__ bhh,
    const float* __restrict__ xg, const int* __restrict__ L,
    unsigned int* tick, unsigned int* flags, float* hF,
    float* __restrict__ out)
{
    unsigned int xcc;
    asm volatile("s_getreg_b32 %0, hwreg(HW_REG_XCC_ID)" : "=s"(xcc));
    const int g = (int)xcc;               // group = physical XCD 0..7

    __shared__ int s_wg;
    const int tid = threadIdx.x;
    if (tid == 0)
        s_wg = (int)__hip_atomic_fetch_add(&tick[g], 1u, __ATOMIC_RELAXED,
                                           __HIP_MEMORY_SCOPE_AGENT);
    __syncthreads();
    const int wgl = s_wg;
    if (wgl >= GWG) return;               // 16 workers per XCD

    __shared__ __align__(16) float h_lds[H * 6];   // [coord][smp0..3,pad2]
    __shared__ float sred[144 * 5];                // [row][smp,pad]
    __shared__ int LsS[SPG];

    unsigned int* flagsg = flags + g * GWG;
    float*        hFg    = hF + (size_t)g * 6144;

    if (tid < SPG) LsS[tid] = L[g * SPG + tid];
    __syncthreads();
    const int S = max(max(LsS[0], LsS[1]), max(LsS[2], LsS[3]));

    const int q = tid >> 5, kc = tid & 31;   // q in [0,16): half-wave id

    // weights -> VGPRs: this WG owns coords [48*wgl, 48*wgl+48), rows
    // lr in [0,144): gate = lr/48, coord = 48*wgl + lr%48.
    // half-wave q holds rows lr = 9q+j; per lane w[9][24] = 216 VGPR (as R12).
    float w[9][24];
#pragma unroll
    for (int j = 0; j < 9; ++j) {
        const int lr = q * 9 + j;
        const int row = (lr / 48) * H + 48 * wgl + (lr % 48);
        const float* wp = Whh + (size_t)row * H + kc;
#pragma unroll
        for (int ki = 0; ki < 24; ++ki) w[j][ki] = wp[ki << 5];
    }

    // gate-thread constants (tid<192: coord cg, sample smp=tid&3)
    float bR = 0.f, bZ = 0.f, bN = 0.f;
    int Lb = 2, cg = 0, b = 0;
    const float* xb = xg;
    if (tid < 192) {
        cg = 48 * wgl + (tid >> 2);
        b  = g * SPG + (tid & 3);
        bR = bhh[cg]; bZ = bhh[H + cg]; bN = bhh[2 * H + cg];
        Lb = LsS[tid & 3];
        xb = xg + (size_t)b * TT * G3 + cg;
    }

    for (int s = 0; s < S; ++s) {
        // ---- xg loads issued first: L3 latency hides under the flag poll ----
        float xr = 0.f, xz = 0.f, xn = 0.f;
        if (tid < 192) {
            const int tt = (s < Lb) ? s : (Lb - 1);
            const float* xp = xb + (size_t)tt * G3;
            xr = xp[0]; xz = xp[H]; xn = xp[2 * H];
        }

        // ---- damper: wave0 polls 16 flags >= s (sc1, proven protocol) ----
        if (s && tid < 64) {
            const unsigned int* fp = flagsg + (tid & 15);
            int spins = 0;
            for (;;) {
                unsigned int v;
                asm volatile("global_load_dword %0, %1, off sc1\n\t"
                             "s_waitcnt vmcnt(0)"
                             : "=v"(v) : "v"(fp) : "memory");
                if (__all((int)v >= s)) break;
                if (((++spins) & 63) == 0) {      // belt-and-suspenders valve
                    v = __hip_atomic_load(fp, __ATOMIC_RELAXED,
                                          __HIP_MEMORY_SCOPE_AGENT);
                    if (__all((int)v >= s)) break;
                }
                if (spins > 4) __builtin_amdgcn_s_sleep(1);
            }
        }
        __syncthreads();

        // ---- gather 3072 f32: 384 threads x 2 dwordx4 (sc1), exactly once ----
        if (tid < 384) {
            const float* hr = hFg + (s & 1) * 3072 + 8 * tid;
            vf4 a0, a1;
            asm volatile(
                "global_load_dwordx4 %0, %2, off sc1\n\t"
                "global_load_dwordx4 %1, %2, off offset:16 sc1\n\t"
                "s_waitcnt vmcnt(0)"
                : "=&v"(a0), "=&v"(a1) : "v"(hr) : "memory");
            const int c0 = 2 * tid;                // coords c0, c0+1
            *(float2*)&h_lds[c0 * 6]           = make_float2(a0.x, a0.y);
            *(float2*)&h_lds[c0 * 6 + 2]       = make_float2(a0.z, a0.w);
            *(float2*)&h_lds[(c0 + 1) * 6]     = make_float2(a1.x, a1.y);
            *(float2*)&h_lds[(c0 + 1) * 6 + 2] = make_float2(a1.z, a1.w);
        }
        __syncthreads();                               // syncA

        // hp read pulled before syncB (LDS rewritten only after next gather)
        float hp = 0.f;
        if (tid < 192) hp = h_lds[cg * 6 + (tid & 3)];

        // ---- dot: 24 x (2 ds_read_b64 + 36 fma) — identical to R12 ----
        float acc[9][4] = {};
#pragma unroll
        for (int ki = 0; ki < 24; ++ki) {
            const int k6 = (kc + (ki << 5)) * 6;
            const float2 h01 = *(const float2*)&h_lds[k6];
            const float2 h23 = *(const float2*)&h_lds[k6 + 2];
#pragma unroll
            for (int j = 0; j < 9; ++j) {
                const float wv = w[j][ki];
                acc[j][0] = fmaf(wv, h01.x, acc[j][0]);
                acc[j][1] = fmaf(wv, h01.y, acc[j][1]);
                acc[j][2] = fmaf(wv, h23.x, acc[j][2]);
                acc[j][3] = fmaf(wv, h23.y, acc[j][3]);
            }
        }
        // ---- reduce over kc (xor 1..16 stays in 32-lane half) ----
#pragma unroll
        for (int j = 0; j < 9; ++j)
#pragma unroll
            for (int m = 0; m < 4; ++m) {
                float x = acc[j][m];
                x += __shfl_xor(x, 1);
                x += __shfl_xor(x, 2);
                x += __shfl_xor(x, 4);
                x += __shfl_xor(x, 8);
                x += __shfl_xor(x, 16);
                acc[j][m] = x;
            }
        if (kc == 0) {
#pragma unroll
            for (int j = 0; j < 9; ++j)
#pragma unroll
                for (int m = 0; m < 4; ++m)
                    sred[(q * 9 + j) * 5 + m] = acc[j][m];
        }
        __syncthreads();                               // syncB

        // ---- gates + publish (rows: gate0 = c, gate1 = 48+c, gate2 = 96+c) --
        float* hw = hFg + ((s + 1) & 1) * 3072;
        if (tid < 192) {
            const int c = tid >> 2, smp = tid & 3;
            const float sr = sred[(c) * 5 + smp]      + bR;
            const float sz = sred[(48 + c) * 5 + smp] + bZ;
            const float sn = sred[(96 + c) * 5 + smp] + bN;
            const float rg = 1.f / (1.f + expf(-(xr + sr)));
            const float zg = 1.f / (1.f + expf(-(xz + sz)));
            const float ng = tanhf(xn + rg * sn);
            const float hn = (s < Lb) ? ((1.f - zg) * ng + zg * hp) : hp;
            __hip_atomic_store(&hw[cg * 4 + smp], hn, __ATOMIC_RELAXED,
                               __HIP_MEMORY_SCOPE_WORKGROUP);
            if (s == Lb - 1) {
                out[b * H + cg] = hn;                     // outputs[b]
                if (b == BS - 1) out[BS * H + cg] = hn;   // hF == outputs[31]
            }
        }
        __syncthreads();    // drains publish stores (vmcnt(0) before s_barrier)
        if (tid == 0)
            __hip_atomic_store(&flagsg[wgl], (unsigned int)(s + 1),
                               __ATOMIC_RELAXED, __HIP_MEMORY_SCOPE_WORKGROUP);
    }
}

extern "C" void kernel_launch(void* const* d_in, const int* in_sizes, int n_in,
                              void* d_out, int out_size, void* d_ws, size_t ws_size,
                              hipStream_t stream) {
    const float* emb  = (const float*)d_in[0];   // [32][512][768]
    const int*   mask = (const int*)d_in[1];     // [32][512]
    const float* gctx = (const float*)d_in[2];   // [1][1][768]
    const float* Wih  = (const float*)d_in[3];   // [2304][768]
    const float* Whh  = (const float*)d_in[4];   // [2304][768]
    const float* bih  = (const float*)d_in[5];   // [2304]
    const float* bhh  = (const float*)d_in[6];   // [2304]
    float* out = (float*)d_out;                  // 32*768 + 768 floats

    char* ws = (char*)d_ws;
    float*              xg    = (float*)(ws + WS_XG);
    char*               ctrl  = ws + WS_CTRL;
    unsigned int*       tick  = (unsigned int*)(ctrl + CT_TICK);
    unsigned int*       flags = (unsigned int*)(ctrl + CT_FLAGS);
    int*                L     = (int*)(ctrl + CT_L);
    float*              hF    = (float*)(ctrl + CT_HB);

    prep_kernel<<<BS, 256, 0, stream>>>(mask, gctx, L, tick, flags, hF);
    xg_gemm<<<dim3(256, 36), 256, 0, stream>>>(emb, Wih, bih, L, xg);
    gru_kernel<<<GRID_GRU, 512, 0, stream>>>(Whh, bhh, xg, L, tick, flags, hF, out);
}

// Round 9
// 8363.387 us; speedup vs baseline: 1.0045x; 1.0045x over previous
//
// R18: R17 with the launch-bounds bug fixed. R17's __launch_bounds__(512,2)
// means *2 waves min per SIMD* (not 2 blocks/CU) -> 4 waves/SIMD -> 128 VGPR
// cap -> the 216-reg w[9][24] spilled to scratch -> every step re-streamed
// weights from HBM (FETCH_SIZE 66MB->9.28GB, 7.6ms). Fix: (512,1) -> 2
// waves/SIMD -> 256 VGPR/lane, weights stay resident (VGPR-forced 1 WG/CU:
// 8 waves x 256 VGPR fills the CU pool). Everything else byte-identical to
// R17, making this the clean A/B for the participant-width hypothesis:
// 16 WGs x 512 thr vs R12's 32 WGs x 256 thr (1985us). Halved: exchange
// width (skew max-of-16), flags, XCD sc1 requests (12.3K vs 24.6K),
// publisher count. Same per-thread compute as R12 (864 FMA, 180 shfl).
#include <hip/hip_runtime.h>
#include <cstdint>
#include <cstddef>

#define H    768
#define G3   2304
#define TT   512
#define BS   32
#define NGRP 8
#define GWG  16        // worker WGs per group (512 threads each, 16 CUs used)
#define SPG  4         // samples per group
#define GRID_GRU 512   // oversubscribed; ticket winners persist

// ctrl block inside xg dead zone (b=0, t>=384; L[0]~256 => never touched)
#define WS_XG    0
#define WS_CTRL  3538944                 // byte offset of xg[0][384][0]
#define CT_TICK  0                       // uint[8]
#define CT_FLAGS 64                      // uint[8][16] = 512 B
#define CT_L     1088                    // int[32]
#define CT_HB    1280                    // float[8][2][3072] = 196608 B

typedef float vf4 __attribute__((ext_vector_type(4)));

// ---------------- phase 1: lengths + tickets/flags + hF buf0 seed -------------
__global__ void prep_kernel(const int* __restrict__ mask, const float* __restrict__ gc,
                            int* __restrict__ L, unsigned int* __restrict__ tick,
                            unsigned int* __restrict__ flags,
                            float* __restrict__ hF) {
    __shared__ int sbuf[256];
    const int b = blockIdx.x, tid = threadIdx.x;
    int c = 0;
    for (int t = tid; t < TT; t += 256) c += (mask[b * TT + t] != 0) ? 1 : 0;
    sbuf[tid] = c;
    __syncthreads();
    for (int off = 128; off > 0; off >>= 1) {
        if (tid < off) sbuf[tid] += sbuf[tid + off];
        __syncthreads();
    }
    if (tid == 0) {
        int l = sbuf[0];
        if (l < 1) l = 2;              // reference: where(L<1, 2, L)
        L[b] = l;
    }
    if (b == 0 && tid < NGRP) tick[tid] = 0u;
    if (tid < 4) flags[b * 4 + tid] = 0u;          // 32 blocks x 4 = 128
    // seed hF[g][buf0][r] = gc[r>>2]: 24576 floats, 768 per block (r = c*4+smp)
    for (int i = tid; i < 768; i += 256) {
        const int e = b * 768 + i;                 // 0..24575
        const int g = e / 3072, r = e - g * 3072;
        hF[g * 6144 + r] = gc[r >> 2];
    }
}

// ---------------- phase 2: xg = emb @ W_ih^T + b_ih (unchanged) ----------------
__global__ __launch_bounds__(256) void xg_gemm(
    const float* __restrict__ A, const float* __restrict__ W,
    const float* __restrict__ bih, const int* __restrict__ L,
    float* __restrict__ xg)
{
    const int mt = blockIdx.x, nt = blockIdx.y;
    const int b  = mt >> 3;
    const int t0 = (mt & 7) << 6;
    if (t0 >= L[b]) return;

    __shared__ __align__(16) float As[16][68];
    __shared__ __align__(16) float Bsh[16][68];

    const int tid = threadIdx.x;
    const int m0 = mt << 6, n0 = nt << 6;
    const int lr = tid >> 2;
    const int lk = (tid & 3) << 2;
    const int tm = (tid >> 4) << 2;
    const int tn = (tid & 15) << 2;

    float c[4][4] = {};
    const float* Ap = A + (size_t)(m0 + lr) * H + lk;
    const float* Wp = W + (size_t)(n0 + lr) * H + lk;

    for (int k0 = 0; k0 < H; k0 += 16) {
        float4 av = *(const float4*)(Ap + k0);
        float4 bv = *(const float4*)(Wp + k0);
        As[lk + 0][lr] = av.x; As[lk + 1][lr] = av.y;
        As[lk + 2][lr] = av.z; As[lk + 3][lr] = av.w;
        Bsh[lk + 0][lr] = bv.x; Bsh[lk + 1][lr] = bv.y;
        Bsh[lk + 2][lr] = bv.z; Bsh[lk + 3][lr] = bv.w;
        __syncthreads();
#pragma unroll
        for (int kk = 0; kk < 16; ++kk) {
            float4 a4 = *(const float4*)&As[kk][tm];
            float4 b4 = *(const float4*)&Bsh[kk][tn];
            c[0][0] = fmaf(a4.x, b4.x, c[0][0]); c[0][1] = fmaf(a4.x, b4.y, c[0][1]);
            c[0][2] = fmaf(a4.x, b4.z, c[0][2]); c[0][3] = fmaf(a4.x, b4.w, c[0][3]);
            c[1][0] = fmaf(a4.y, b4.x, c[1][0]); c[1][1] = fmaf(a4.y, b4.y, c[1][1]);
            c[1][2] = fmaf(a4.y, b4.z, c[1][2]); c[1][3] = fmaf(a4.y, b4.w, c[1][3]);
            c[2][0] = fmaf(a4.z, b4.x, c[2][0]); c[2][1] = fmaf(a4.z, b4.y, c[2][1]);
            c[2][2] = fmaf(a4.z, b4.z, c[2][2]); c[2][3] = fmaf(a4.z, b4.w, c[2][3]);
            c[3][0] = fmaf(a4.w, b4.x, c[3][0]); c[3][1] = fmaf(a4.w, b4.y, c[3][1]);
            c[3][2] = fmaf(a4.w, b4.z, c[3][2]); c[3][3] = fmaf(a4.w, b4.w, c[3][3]);
        }
        __syncthreads();
    }
    const float4 bias = *(const float4*)&bih[n0 + tn];
#pragma unroll
    for (int i = 0; i < 4; ++i) {
        float4 o;
        o.x = c[i][0] + bias.x; o.y = c[i][1] + bias.y;
        o.z = c[i][2] + bias.z; o.w = c[i][3] + bias.w;
        *(float4*)&xg[(size_t)(m0 + tm + i) * G3 + n0 + tn] = o;
    }
}

// ---------------- phase 3: per-XCD group of 16 WGs x 512 threads, 4 chains ---
__global__ __launch_bounds__(512, 1) void gru_kernel(
    const float* __restrict__ Whh, const float* __restrict__ bhh,
    const float* __restrict__ xg, const int* __restrict__ L,
    unsigned int* tick, unsigned int* flags, float* hF,
    float* __restrict__ out)
{
    unsigned int xcc;
    asm volatile("s_getreg_b32 %0, hwreg(HW_REG_XCC_ID)" : "=s"(xcc));
    const int g = (int)xcc;               // group = physical XCD 0..7

    __shared__ int s_wg;
    const int tid = threadIdx.x;
    if (tid == 0)
        s_wg = (int)__hip_atomic_fetch_add(&tick[g], 1u, __ATOMIC_RELAXED,
                                           __HIP_MEMORY_SCOPE_AGENT);
    __syncthreads();
    const int wgl = s_wg;
    if (wgl >= GWG) return;               // 16 workers per XCD

    __shared__ __align__(16) float h_lds[H * 6];   // [coord][smp0..3,pad2]
    __shared__ float sred[144 * 5];                // [row][smp,pad]
    __shared__ int LsS[SPG];

    unsigned int* flagsg = flags + g * GWG;
    float*        hFg    = hF + (size_t)g * 6144;

    if (tid < SPG) LsS[tid] = L[g * SPG + tid];
    __syncthreads();
    const int S = max(max(LsS[0], LsS[1]), max(LsS[2], LsS[3]));

    const int q = tid >> 5, kc = tid & 31;   // q in [0,16): half-wave id

    // weights -> VGPRs: this WG owns coords [48*wgl, 48*wgl+48), rows
    // lr in [0,144): gate = lr/48, coord = 48*wgl + lr%48.
    // half-wave q holds rows lr = 9q+j; per lane w[9][24] = 216 VGPR (as R12).
    float w[9][24];
#pragma unroll
    for (int j = 0; j < 9; ++j) {
        const int lr = q * 9 + j;
        const int row = (lr / 48) * H + 48 * wgl + (lr % 48);
        const float* wp = Whh + (size_t)row * H + kc;
#pragma unroll
        for (int ki = 0; ki < 24; ++ki) w[j][ki] = wp[ki << 5];
    }

    // gate-thread constants (tid<192: coord cg, sample smp=tid&3)
    float bR = 0.f, bZ = 0.f, bN = 0.f;
    int Lb = 2, cg = 0, b = 0;
    const float* xb = xg;
    if (tid < 192) {
        cg = 48 * wgl + (tid >> 2);
        b  = g * SPG + (tid & 3);
        bR = bhh[cg]; bZ = bhh[H + cg]; bN = bhh[2 * H + cg];
        Lb = LsS[tid & 3];
        xb = xg + (size_t)b * TT * G3 + cg;
    }

    for (int s = 0; s < S; ++s) {
        // ---- xg loads issued first: L3 latency hides under the flag poll ----
        float xr = 0.f, xz = 0.f, xn = 0.f;
        if (tid < 192) {
            const int tt = (s < Lb) ? s : (Lb - 1);
            const float* xp = xb + (size_t)tt * G3;
            xr = xp[0]; xz = xp[H]; xn = xp[2 * H];
        }

        // ---- damper: wave0 polls 16 flags >= s (sc1, proven protocol) ----
        if (s && tid < 64) {
            const unsigned int* fp = flagsg + (tid & 15);
            int spins = 0;
            for (;;) {
                unsigned int v;
                asm volatile("global_load_dword %0, %1, off sc1\n\t"
                             "s_waitcnt vmcnt(0)"
                             : "=v"(v) : "v"(fp) : "memory");
                if (__all((int)v >= s)) break;
                if (((++spins) & 63) == 0) {      // belt-and-suspenders valve
                    v = __hip_atomic_load(fp, __ATOMIC_RELAXED,
                                          __HIP_MEMORY_SCOPE_AGENT);
                    if (__all((int)v >= s)) break;
                }
                if (spins > 4) __builtin_amdgcn_s_sleep(1);
            }
        }
        __syncthreads();

        // ---- gather 3072 f32: 384 threads x 2 dwordx4 (sc1), exactly once ----
        if (tid < 384) {
            const float* hr = hFg + (s & 1) * 3072 + 8 * tid;
            vf4 a0, a1;
            asm volatile(
                "global_load_dwordx4 %0, %2, off sc1\n\t"
                "global_load_dwordx4 %1, %2, off offset:16 sc1\n\t"
                "s_waitcnt vmcnt(0)"
                : "=&v"(a0), "=&v"(a1) : "v"(hr) : "memory");
            const int c0 = 2 * tid;                // coords c0, c0+1
            *(float2*)&h_lds[c0 * 6]           = make_float2(a0.x, a0.y);
            *(float2*)&h_lds[c0 * 6 + 2]       = make_float2(a0.z, a0.w);
            *(float2*)&h_lds[(c0 + 1) * 6]     = make_float2(a1.x, a1.y);
            *(float2*)&h_lds[(c0 + 1) * 6 + 2] = make_float2(a1.z, a1.w);
        }
        __syncthreads();                               // syncA

        // hp read pulled before syncB (LDS rewritten only after next gather)
        float hp = 0.f;
        if (tid < 192) hp = h_lds[cg * 6 + (tid & 3)];

        // ---- dot: 24 x (2 ds_read_b64 + 36 fma) — identical to R12 ----
        float acc[9][4] = {};
#pragma unroll
        for (int ki = 0; ki < 24; ++ki) {
            const int k6 = (kc + (ki << 5)) * 6;
            const float2 h01 = *(const float2*)&h_lds[k6];
            const float2 h23 = *(const float2*)&h_lds[k6 + 2];
#pragma unroll
            for (int j = 0; j < 9; ++j) {
                const float wv = w[j][ki];
                acc[j][0] = fmaf(wv, h01.x, acc[j][0]);
                acc[j][1] = fmaf(wv, h01.y, acc[j][1]);
                acc[j][2] = fmaf(wv, h23.x, acc[j][2]);
                acc[j][3] = fmaf(wv, h23.y, acc[j][3]);
            }
        }
        // ---- reduce over kc (xor 1..16 stays in 32-lane half) ----
#pragma unroll
        for (int j = 0; j < 9; ++j)
#pragma unroll
            for (int m = 0; m < 4; ++m) {
                float x = acc[j][m];
                x += __shfl_xor(x, 1);
                x += __shfl_xor(x, 2);
                x += __shfl_xor(x, 4);
                x += __shfl_xor(x, 8);
                x += __shfl_xor(x, 16);
                acc[j][m] = x;
            }
        if (kc == 0) {
#pragma unroll
            for (int j = 0; j < 9; ++j)
#pragma unroll
                for (int m = 0; m < 4; ++m)
                    sred[(q * 9 + j) * 5 + m] = acc[j][m];
        }
        __syncthreads();                               // syncB

        // ---- gates + publish (rows: gate0 = c, gate1 = 48+c, gate2 = 96+c) --
        float* hw = hFg + ((s + 1) & 1) * 3072;
        if (tid < 192) {
            const int c = tid >> 2, smp = tid & 3;
            const float sr = sred[(c) * 5 + smp]      + bR;
            const float sz = sred[(48 + c) * 5 + smp] + bZ;
            const float sn = sred[(96 + c) * 5 + smp] + bN;
            const float rg = 1.f / (1.f + expf(-(xr + sr)));
            const float zg = 1.f / (1.f + expf(-(xz + sz)));
            const float ng = tanhf(xn + rg * sn);
            const float hn = (s < Lb) ? ((1.f - zg) * ng + zg * hp) : hp;
            __hip_atomic_store(&hw[cg * 4 + smp], hn, __ATOMIC_RELAXED,
                               __HIP_MEMORY_SCOPE_WORKGROUP);
            if (s == Lb - 1) {
                out[b * H + cg] = hn;                     // outputs[b]
                if (b == BS - 1) out[BS * H + cg] = hn;   // hF == outputs[31]
            }
        }
        __syncthreads();    // drains publish stores (vmcnt(0) before s_barrier)
        if (tid == 0)
            __hip_atomic_store(&flagsg[wgl], (unsigned int)(s + 1),
                               __ATOMIC_RELAXED, __HIP_MEMORY_SCOPE_WORKGROUP);
    }
}

extern "C" void kernel_launch(void* const* d_in, const int* in_sizes, int n_in,
                              void* d_out, int out_size, void* d_ws, size_t ws_size,
                              hipStream_t stream) {
    const float* emb  = (const float*)d_in[0];   // [32][512][768]
    const int*   mask = (const int*)d_in[1];     // [32][512]
    const float* gctx = (const float*)d_in[2];   // [1][1][768]
    const float* Wih  = (const float*)d_in[3];   // [2304][768]
    const float* Whh  = (const float*)d_in[4];   // [2304][768]
    const float* bih  = (const float*)d_in[5];   // [2304]
    const float* bhh  = (const float*)d_in[6];   // [2304]
    float* out = (float*)d_out;                  // 32*768 + 768 floats

    char* ws = (char*)d_ws;
    float*              xg    = (float*)(ws + WS_XG);
    char*               ctrl  = ws + WS_CTRL;
    unsigned int*       tick  = (unsigned int*)(ctrl + CT_TICK);
    unsigned int*       flags = (unsigned int*)(ctrl + CT_FLAGS);
    int*                L     = (int*)(ctrl + CT_L);
    float*              hF    = (float*)(ctrl + CT_HB);

    prep_kernel<<<BS, 256, 0, stream>>>(mask, gctx, L, tick, flags, hF);
    xg_gemm<<<dim3(256, 36), 256, 0, stream>>>(emb, Wih, bih, L, xg);
    gru_kernel<<<GRID_GRU, 512, 0, stream>>>(Whh, bhh, xg, L, tick, flags, hF, out);
}

// Round 10
// 2570.568 us; speedup vs baseline: 3.2681x; 3.2535x over previous
//
// R19: bank the safe win. gru_kernel + prep reverted byte-identical to R12
// (best passing: gru 1985us, total 2704us). The 512-thread participant-width
// experiment (R17/R18) is architecturally dead: an 8-wave workgroup forces
// 2 waves/SIMD -> 128 arch-VGPR cap -> w[9][24] (216 regs) cannot be
// resident; both rounds spilled to scratch (FETCH 9.3GB). The untouched cost
// is xg_gemm: 64x64-tile fp32 GEMM at ~45TF = ~650us. Rebuilt as 128x128
// tile / BK=16 / 256 threads / 8x8 acc: 4 ds_read_b128 per kk feed 64 FMAs
// (16:1 FMA:LDS), 4+4 column split keeps LDS reads at <=2-way conflicts
// (free). Same t0>=L[b] guard keeps the ctrl block (xg dead zone, t>=384)
// unwritten. Expected xg_gemm ~300us -> total ~2350us.
#include <hip/hip_runtime.h>
#include <cstdint>
#include <cstddef>

#define H    768
#define G3   2304
#define TT   512
#define BS   32
#define NGRP 8
#define GWG  32        // worker WGs per group (one per CU on the XCD)
#define SPG  4         // samples per group
#define GRID_GRU 2048  // oversubscribed; ticket winners persist

// dynamic LDS pad: 19968 static + 62464 = 82432 > 81920 => 1 WG/CU
#define LDS_PAD  62464

// ctrl block inside xg dead zone (b=0, t>=384; L[0]~256 => never touched)
#define WS_XG    0
#define WS_CTRL  3538944                 // byte offset of xg[0][384][0]
#define CT_TICK  0                       // uint[8]
#define CT_FLAGS 64                      // uint[8][32]
#define CT_L     1088                    // int[32]
#define CT_HB    1280                    // float[8][2][3072] = 196608 B

typedef float vf4 __attribute__((ext_vector_type(4)));

// ---------------- phase 1: lengths + tickets/flags + hF buf0 seed -------------
__global__ void prep_kernel(const int* __restrict__ mask, const float* __restrict__ gc,
                            int* __restrict__ L, unsigned int* __restrict__ tick,
                            unsigned int* __restrict__ flags,
                            float* __restrict__ hF) {
    __shared__ int sbuf[256];
    const int b = blockIdx.x, tid = threadIdx.x;
    int c = 0;
    for (int t = tid; t < TT; t += 256) c += (mask[b * TT + t] != 0) ? 1 : 0;
    sbuf[tid] = c;
    __syncthreads();
    for (int off = 128; off > 0; off >>= 1) {
        if (tid < off) sbuf[tid] += sbuf[tid + off];
        __syncthreads();
    }
    if (tid == 0) {
        int l = sbuf[0];
        if (l < 1) l = 2;              // reference: where(L<1, 2, L)
        L[b] = l;
    }
    if (b == 0 && tid < NGRP) tick[tid] = 0u;
    if (tid < 8) flags[b * 8 + tid] = 0u;          // 32 blocks x 8 = 256
    // seed hF[g][buf0][r] = gc[r>>2]: 24576 floats, 768 per block (r = c*4+smp)
    for (int i = tid; i < 768; i += 256) {
        const int e = b * 768 + i;                 // 0..24575
        const int g = e / 3072, r = e - g * 3072;
        hF[g * 6144 + r] = gc[r >> 2];
    }
}

// ---------------- phase 2: xg = emb @ W_ih^T + b_ih — 128x128 tile ------------
__global__ __launch_bounds__(256) void xg_gemm(
    const float* __restrict__ A, const float* __restrict__ W,
    const float* __restrict__ bih, const int* __restrict__ L,
    float* __restrict__ xg)
{
    const int mt = blockIdx.x, nt = blockIdx.y;
    const int b  = mt >> 2;              // 4 tiles of 128 rows per sample (512)
    const int t0 = (mt & 3) << 7;
    if (t0 >= L[b]) return;              // also protects the ctrl dead zone

    __shared__ __align__(16) float As[16][132];
    __shared__ __align__(16) float Ws[16][132];

    const int tid = threadIdx.x;
    const int m0 = mt << 7, n0 = nt << 7;
    const int lr = tid >> 2;             // 0..63
    const int lk = (tid & 3) << 2;       // 0,4,8,12
    const int tx = tid & 15, ty = tid >> 4;
    const int cx = tx << 2, cy = ty << 2;

    float c[8][8] = {};
    const float* Ap = A + (size_t)(m0 + lr) * H + lk;
    const float* Wp = W + (size_t)(n0 + lr) * H + lk;

    for (int k0 = 0; k0 < H; k0 += 16) {
        const float4 a0 = *(const float4*)(Ap + k0);
        const float4 a1 = *(const float4*)(Ap + (size_t)64 * H + k0);
        const float4 w0 = *(const float4*)(Wp + k0);
        const float4 w1 = *(const float4*)(Wp + (size_t)64 * H + k0);
        As[lk + 0][lr] = a0.x; As[lk + 1][lr] = a0.y;
        As[lk + 2][lr] = a0.z; As[lk + 3][lr] = a0.w;
        As[lk + 0][64 + lr] = a1.x; As[lk + 1][64 + lr] = a1.y;
        As[lk + 2][64 + lr] = a1.z; As[lk + 3][64 + lr] = a1.w;
        Ws[lk + 0][lr] = w0.x; Ws[lk + 1][lr] = w0.y;
        Ws[lk + 2][lr] = w0.z; Ws[lk + 3][lr] = w0.w;
        Ws[lk + 0][64 + lr] = w1.x; Ws[lk + 1][64 + lr] = w1.y;
        Ws[lk + 2][64 + lr] = w1.z; Ws[lk + 3][64 + lr] = w1.w;
        __syncthreads();
#pragma unroll
        for (int kk = 0; kk < 16; ++kk) {
            const float4 xa0 = *(const float4*)&As[kk][cy];
            const float4 xa1 = *(const float4*)&As[kk][64 + cy];
            const float4 xb0 = *(const float4*)&Ws[kk][cx];
            const float4 xb1 = *(const float4*)&Ws[kk][64 + cx];
            const float av[8] = {xa0.x, xa0.y, xa0.z, xa0.w,
                                 xa1.x, xa1.y, xa1.z, xa1.w};
            const float bv[8] = {xb0.x, xb0.y, xb0.z, xb0.w,
                                 xb1.x, xb1.y, xb1.z, xb1.w};
#pragma unroll
            for (int i = 0; i < 8; ++i)
#pragma unroll
                for (int j = 0; j < 8; ++j)
                    c[i][j] = fmaf(av[i], bv[j], c[i][j]);
        }
        __syncthreads();
    }
    const float4 bb0 = *(const float4*)&bih[n0 + cx];
    const float4 bb1 = *(const float4*)&bih[n0 + 64 + cx];
#pragma unroll
    for (int i = 0; i < 8; ++i) {
        const int r = m0 + ((i < 4) ? (cy + i) : (64 + cy + i - 4));
        float* cp = xg + (size_t)r * G3 + n0;
        float4 o0, o1;
        o0.x = c[i][0] + bb0.x; o0.y = c[i][1] + bb0.y;
        o0.z = c[i][2] + bb0.z; o0.w = c[i][3] + bb0.w;
        o1.x = c[i][4] + bb1.x; o1.y = c[i][5] + bb1.y;
        o1.z = c[i][6] + bb1.z; o1.w = c[i][7] + bb1.w;
        *(float4*)(cp + cx) = o0;
        *(float4*)(cp + 64 + cx) = o1;
    }
}

// ---------------- phase 3: per-XCD group of 32 WGs, 4 chains (== R12) --------
__global__ __launch_bounds__(256, 1) void gru_kernel(
    const float* __restrict__ Whh, const float* __restrict__ bhh,
    const float* __restrict__ xg, const int* __restrict__ L,
    unsigned int* tick, unsigned int* flags, float* hF,
    float* __restrict__ out)
{
    extern __shared__ char lds_occupancy_pad[];   // forces 1 WG/CU
    (void)lds_occupancy_pad;

    unsigned int xcc;
    asm volatile("s_getreg_b32 %0, hwreg(HW_REG_XCC_ID)" : "=s"(xcc));
    const int g = (int)xcc;               // group = physical XCD 0..7

    __shared__ int s_wg;
    const int tid = threadIdx.x;
    if (tid == 0)
        s_wg = (int)__hip_atomic_fetch_add(&tick[g], 1u, __ATOMIC_RELAXED,
                                           __HIP_MEMORY_SCOPE_AGENT);
    __syncthreads();
    const int wgl = s_wg;
    if (wgl >= GWG) return;               // 32 workers per XCD

    __shared__ __align__(16) float h_lds[H * 6];   // [coord][smp0..3,pad2]
    __shared__ float sred[72 * 5];                 // [lr][smp,pad]
    __shared__ int LsS[SPG];

    unsigned int* flagsg = flags + g * GWG;
    float*        hFg    = hF + (size_t)g * 6144;

    if (tid < SPG) LsS[tid] = L[g * SPG + tid];
    __syncthreads();
    const int S = max(max(LsS[0], LsS[1]), max(LsS[2], LsS[3]));

    const int q = tid >> 5, kc = tid & 31;

    // weights -> VGPRs: w[j][ki] = Whh[row(q*9+j)][kc+32*ki]
    float w[9][24];
#pragma unroll
    for (int j = 0; j < 9; ++j) {
        const int lr = q * 9 + j;
        const int row = (lr / 24) * H + 24 * wgl + (lr % 24);
        const float* wp = Whh + (size_t)row * H + kc;
#pragma unroll
        for (int ki = 0; ki < 24; ++ki) w[j][ki] = wp[ki << 5];
    }

    // gate-thread constants (tid<96: coord cg, sample smp=tid&3)
    float bR = 0.f, bZ = 0.f, bN = 0.f;
    int Lb = 2, cg = 0, b = 0;
    const float* xb = xg;
    if (tid < 96) {
        cg = 24 * wgl + (tid >> 2);
        b  = g * SPG + (tid & 3);
        bR = bhh[cg]; bZ = bhh[H + cg]; bN = bhh[2 * H + cg];
        Lb = LsS[tid & 3];
        xb = xg + (size_t)b * TT * G3 + cg;
    }

    const int c0 = 3 * tid;               // this thread gathers coords c0..c0+2

    for (int s = 0; s < S; ++s) {
        // ---- xg loads issued first: L3 latency hides under the flag poll ----
        float xr = 0.f, xz = 0.f, xn = 0.f;
        if (tid < 96) {
            const int tt = (s < Lb) ? s : (Lb - 1);
            const float* xp = xb + (size_t)tt * G3;
            xr = xp[0]; xz = xp[H]; xn = xp[2 * H];
        }

        // ---- damper: wave0 polls 32 flags >= s (DEVICE scope, tiny traffic) --
        if (s && tid < 64) {
            const unsigned int* fp = flagsg + (tid & 31);
            int spins = 0;
            for (;;) {
                unsigned int v;
                asm volatile("global_load_dword %0, %1, off sc1\n\t"
                             "s_waitcnt vmcnt(0)"
                             : "=v"(v) : "v"(fp) : "memory");
                if (__all((int)v >= s)) break;
                if (((++spins) & 63) == 0) {      // belt-and-suspenders valve
                    v = __hip_atomic_load(fp, __ATOMIC_RELAXED,
                                          __HIP_MEMORY_SCOPE_AGENT);
                    if (__all((int)v >= s)) break;
                }
                if (spins > 4) __builtin_amdgcn_s_sleep(1);
            }
        }
        __syncthreads();

        // ---- gather 12 f32 in 3 dwordx4 (sc1), exactly once: flags proved
        //      the data is in L2. ----
        const float* hr = hFg + (s & 1) * 3072 + 12 * tid;
        vf4 a0, a1, a2;
        asm volatile(
            "global_load_dwordx4 %0, %3, off sc1\n\t"
            "global_load_dwordx4 %1, %3, off offset:16 sc1\n\t"
            "global_load_dwordx4 %2, %3, off offset:32 sc1\n\t"
            "s_waitcnt vmcnt(0)"
            : "=&v"(a0), "=&v"(a1), "=&v"(a2)
            : "v"(hr) : "memory");
        *(float2*)&h_lds[c0 * 6]           = make_float2(a0.x, a0.y);
        *(float2*)&h_lds[c0 * 6 + 2]       = make_float2(a0.z, a0.w);
        *(float2*)&h_lds[(c0 + 1) * 6]     = make_float2(a1.x, a1.y);
        *(float2*)&h_lds[(c0 + 1) * 6 + 2] = make_float2(a1.z, a1.w);
        *(float2*)&h_lds[(c0 + 2) * 6]     = make_float2(a2.x, a2.y);
        *(float2*)&h_lds[(c0 + 2) * 6 + 2] = make_float2(a2.z, a2.w);
        __syncthreads();                               // syncA

        // hp read pulled before syncB (LDS rewritten only after next gather)
        float hp = 0.f;
        if (tid < 96) hp = h_lds[cg * 6 + (tid & 3)];

        // ---- dot: 24 x (2 ds_read_b64 + 36 fma) ----
        float acc[9][4] = {};
#pragma unroll
        for (int ki = 0; ki < 24; ++ki) {
            const int k6 = (kc + (ki << 5)) * 6;
            const float2 h01 = *(const float2*)&h_lds[k6];
            const float2 h23 = *(const float2*)&h_lds[k6 + 2];
#pragma unroll
            for (int j = 0; j < 9; ++j) {
                const float wv = w[j][ki];
                acc[j][0] = fmaf(wv, h01.x, acc[j][0]);
                acc[j][1] = fmaf(wv, h01.y, acc[j][1]);
                acc[j][2] = fmaf(wv, h23.x, acc[j][2]);
                acc[j][3] = fmaf(wv, h23.y, acc[j][3]);
            }
        }
        // ---- reduce over kc (xor 1..16 stays in 32-lane half) ----
#pragma unroll
        for (int j = 0; j < 9; ++j)
#pragma unroll
            for (int m = 0; m < 4; ++m) {
                float x = acc[j][m];
                x += __shfl_xor(x, 1);
                x += __shfl_xor(x, 2);
                x += __shfl_xor(x, 4);
                x += __shfl_xor(x, 8);
                x += __shfl_xor(x, 16);
                acc[j][m] = x;
            }
        if (kc == 0) {
#pragma unroll
            for (int j = 0; j < 9; ++j)
#pragma unroll
                for (int m = 0; m < 4; ++m)
                    sred[(q * 9 + j) * 5 + m] = acc[j][m];
        }
        __syncthreads();                               // syncB

        // ---- gates + publish (plain f32 workgroup-scope stores: L2-resident)
        float* hw = hFg + ((s + 1) & 1) * 3072;
        if (tid < 96) {
            const int c = tid >> 2, smp = tid & 3;
            const float sr = sred[(c) * 5 + smp]      + bR;
            const float sz = sred[(24 + c) * 5 + smp] + bZ;
            const float sn = sred[(48 + c) * 5 + smp] + bN;
            const float rg = 1.f / (1.f + expf(-(xr + sr)));
            const float zg = 1.f / (1.f + expf(-(xz + sz)));
            const float ng = tanhf(xn + rg * sn);
            const float hn = (s < Lb) ? ((1.f - zg) * ng + zg * hp) : hp;
            __hip_atomic_store(&hw[cg * 4 + smp], hn, __ATOMIC_RELAXED,
                               __HIP_MEMORY_SCOPE_WORKGROUP);
            if (s == Lb - 1) {
                out[b * H + cg] = hn;                     // outputs[b]
                if (b == BS - 1) out[BS * H + cg] = hn;   // hF == outputs[31]
            }
        }
        __syncthreads();    // drains publish stores (vmcnt(0) before s_barrier)
        if (tid == 0)
            __hip_atomic_store(&flagsg[wgl], (unsigned int)(s + 1),
                               __ATOMIC_RELAXED, __HIP_MEMORY_SCOPE_WORKGROUP);
    }
}

extern "C" void kernel_launch(void* const* d_in, const int* in_sizes, int n_in,
                              void* d_out, int out_size, void* d_ws, size_t ws_size,
                              hipStream_t stream) {
    const float* emb  = (const float*)d_in[0];   // [32][512][768]
    const int*   mask = (const int*)d_in[1];     // [32][512]
    const float* gctx = (const float*)d_in[2];   // [1][1][768]
    const float* Wih  = (const float*)d_in[3];   // [2304][768]
    const float* Whh  = (const float*)d_in[4];   // [2304][768]
    const float* bih  = (const float*)d_in[5];   // [2304]
    const float* bhh  = (const float*)d_in[6];   // [2304]
    float* out = (float*)d_out;                  // 32*768 + 768 floats

    char* ws = (char*)d_ws;
    float*              xg    = (float*)(ws + WS_XG);
    char*               ctrl  = ws + WS_CTRL;
    unsigned int*       tick  = (unsigned int*)(ctrl + CT_TICK);
    unsigned int*       flags = (unsigned int*)(ctrl + CT_FLAGS);
    int*                L     = (int*)(ctrl + CT_L);
    float*              hF    = (float*)(ctrl + CT_HB);

    prep_kernel<<<BS, 256, 0, stream>>>(mask, gctx, L, tick, flags, hF);
    xg_gemm<<<dim3(128, 18), 256, 0, stream>>>(emb, Wih, bih, L, xg);
    gru_kernel<<<GRID_GRU, 256, LDS_PAD, stream>>>(Whh, bhh, xg, L, tick, flags, hF, out);
}